// Round 1
// 1538.698 us; speedup vs baseline: 1.1884x; 1.1884x over previous
//
#include <hip/hip_runtime.h>
#include <cstdint>

#define S_LEN 2048
#define D_K   64
#define M_Q   16      // query rows per workgroup (was 32: halves LDS -> 2 blocks/CU)
#define SSTR  2056    // sS row stride (bf16 elems): 16B-aligned rows + bank spread
#define LOG2E 1.44269504088896340736f

typedef __attribute__((ext_vector_type(8))) short short8;  // 8 x bf16 (4 VGPRs)
typedef __attribute__((ext_vector_type(4))) float f4;

__device__ __forceinline__ short f2b(float f) {   // fp32 -> bf16 (RNE)
    union { float f; uint32_t u; } x; x.f = f;
    uint32_t r = x.u + 0x7FFFu + ((x.u >> 16) & 1u);
    return (short)(r >> 16);
}
__device__ __forceinline__ float b2f(short b) {
    union { uint32_t u; float f; } x;
    x.u = ((uint32_t)(uint16_t)b) << 16;
    return x.f;
}

// 64x64 tile transpose + fp32->bf16 convert (runs once; removes per-block f2b storms).
// tileAlongRow=0: tiles step along input cols (K: [64][2048] -> Kbf [2048][64])
// tileAlongRow=1: tiles step along input rows (V: [2048][64] -> Vt  [64][2048])
__global__ __launch_bounds__(256) void transpose_cvt(
    const float* __restrict__ in, short* __restrict__ out,
    int inRS, int outRS, int tileAlongRow)
{
    __shared__ short T[64][72];   // stride 144 B: keeps short8 LDS reads 16B-aligned
    const int head = blockIdx.x >> 5;    // 32 tiles per head
    const int tile = blockIdx.x & 31;
    const int r0 = tileAlongRow ? tile * 64 : 0;
    const int c0 = tileAlongRow ? 0 : tile * 64;
    const size_t hoff = (size_t)head * S_LEN * D_K;
    const int rr = threadIdx.x >> 2;
    const int cc = (threadIdx.x & 3) * 16;
    const float* ip = in + hoff + (size_t)(r0 + rr) * inRS + c0 + cc;
    #pragma unroll
    for (int j4 = 0; j4 < 4; ++j4) {
        f4 x = *(const f4*)(ip + j4 * 4);
        #pragma unroll
        for (int j = 0; j < 4; ++j) T[cc + j4 * 4 + j][rr] = f2b(x[j]);
    }
    __syncthreads();
    short* op = out + hoff + (size_t)(c0 + rr) * outRS + r0 + cc;
    *(short8*)(op)     = *(const short8*)(&T[rr][cc]);
    *(short8*)(op + 8) = *(const short8*)(&T[rr][cc + 8]);
}

template<bool BF16>
__global__ __launch_bounds__(256, 2) void attn_fused(
    const float* __restrict__ qg, const float* __restrict__ kg,
    const float* __restrict__ vg, const short* __restrict__ kbg,
    const short* __restrict__ vtg, const int* __restrict__ mg,
    float* __restrict__ ctxg, float* __restrict__ attng)
{
    __shared__ short sS[M_Q * SSTR];   // 65,792 B -> 2 blocks/CU

    const int tid  = threadIdx.x;
    const int wave = tid >> 6;
    const int lane = tid & 63;
    const int quad = lane >> 4;
    const int l16  = lane & 15;

    const int bh = blockIdx.x >> 7;   // (b*H + h), 0..63
    const int qt = blockIdx.x & 127;  // query tile fast index -> same-head blocks adjacent (L2)

    const float* qp = qg + (size_t)bh * S_LEN * D_K + (size_t)qt * M_Q * D_K;
    const float* kp = kg + (size_t)bh * D_K * S_LEN;           // K fp32 [d][t] (fallback)
    const float* vp = vg + (size_t)bh * S_LEN * D_K;           // V fp32 [t][d] (fallback)
    const short* kb = kbg + (size_t)bh * S_LEN * D_K;          // K bf16 [t][d]
    const short* vt = vtg + (size_t)bh * D_K * S_LEN;          // V bf16 [d][t]
    const int*   mp = mg + (size_t)(bh >> 4) * S_LEN;
    float* cp = ctxg + (size_t)bh * S_LEN * D_K + (size_t)qt * M_Q * D_K;
    float* ap = attng + ((size_t)bh * S_LEN + (size_t)qt * M_Q) * S_LEN;

    // ---- Q frags straight into registers (no LDS, no barrier) ----
    short8 aq[2];
    #pragma unroll
    for (int h = 0; h < 2; ++h) {
        f4 x0 = *(const f4*)(qp + l16 * D_K + h * 32 + quad * 8);
        f4 x1 = *(const f4*)(qp + l16 * D_K + h * 32 + quad * 8 + 4);
        #pragma unroll
        for (int j = 0; j < 4; ++j) { aq[h][j] = f2b(x0[j]); aq[h][4 + j] = f2b(x1[j]); }
    }

    // ---- phase 1: scores = scale*Q.K, mask -> sS (bf16) ----
    for (int cblk = 0; cblk < 32; ++cblk) {
        const int t0 = (wave * 32 + cblk) * 16;
        const int t  = t0 + l16;
        const int mk = mp[t];
        short8 blo, bhi;   // B[k=d][n=t]: lane = col t, elems = 8 consecutive d per quad
        if (BF16) {
            blo = *(const short8*)(kb + (size_t)t * D_K + quad * 8);
            bhi = *(const short8*)(kb + (size_t)t * D_K + 32 + quad * 8);
        } else {
            #pragma unroll
            for (int j = 0; j < 8; ++j) {
                blo[j] = f2b(kp[(size_t)(quad * 8 + j) * S_LEN + t]);
                bhi[j] = f2b(kp[(size_t)(32 + quad * 8 + j) * S_LEN + t]);
            }
        }
        f4 acc = {0.f, 0.f, 0.f, 0.f};
        acc = __builtin_amdgcn_mfma_f32_16x16x32_bf16(aq[0], blo, acc, 0, 0, 0);
        acc = __builtin_amdgcn_mfma_f32_16x16x32_bf16(aq[1], bhi, acc, 0, 0, 0);
        #pragma unroll
        for (int rr = 0; rr < 4; ++rr) {
            const int row = quad * 4 + rr;   // C/D: row=(lane>>4)*4+reg
            const float val = mk ? -1e9f : acc[rr] * 0.125f;
            sS[row * SSTR + t] = f2b(val);
        }
    }
    __syncthreads();

    // ---- phase 2: row softmax; fp32 attn out (nontemporal) + bf16 p back to sS ----
    {
        const int r = tid >> 4;   // row 0..15, 16 threads per row (same wave)
        const int i = tid & 15;
        short* srow = &sS[r * SSTR];
        float mx = -3.0e38f;
        for (int kk = 0; kk < 16; ++kk) {
            short8 x = *(const short8*)(srow + 8 * i + 128 * kk);
            #pragma unroll
            for (int j = 0; j < 8; ++j) mx = fmaxf(mx, b2f(x[j]));
        }
        mx = fmaxf(mx, __shfl_xor(mx, 1));
        mx = fmaxf(mx, __shfl_xor(mx, 2));
        mx = fmaxf(mx, __shfl_xor(mx, 4));
        mx = fmaxf(mx, __shfl_xor(mx, 8));
        float sum = 0.f;
        for (int kk = 0; kk < 16; ++kk) {
            short8 x = *(const short8*)(srow + 8 * i + 128 * kk);
            #pragma unroll
            for (int j = 0; j < 8; ++j)
                sum += __builtin_amdgcn_exp2f((b2f(x[j]) - mx) * LOG2E);
        }
        sum += __shfl_xor(sum, 1);
        sum += __shfl_xor(sum, 2);
        sum += __shfl_xor(sum, 4);
        sum += __shfl_xor(sum, 8);
        const float inv = 1.0f / sum;
        float* arow = ap + (size_t)r * S_LEN;
        for (int kk = 0; kk < 16; ++kk) {
            const int c0 = 8 * i + 128 * kk;
            short8 x = *(const short8*)(srow + c0);
            short8 pb;
            f4 o0, o1;
            #pragma unroll
            for (int j = 0; j < 8; ++j) {
                const float e = __builtin_amdgcn_exp2f((b2f(x[j]) - mx) * LOG2E) * inv;
                pb[j] = f2b(e);
                if (j < 4) o0[j] = e; else o1[j - 4] = e;
            }
            *(short8*)(srow + c0) = pb;                        // p (bf16) for PV
            __builtin_nontemporal_store(o0, (f4*)(arow + c0));     // streaming 1 GB
            __builtin_nontemporal_store(o1, (f4*)(arow + c0 + 4));
        }
    }
    __syncthreads();

    // ---- phase 3: context = P.V ; d-split across waves (16 cols each, full K) ----
    // No cross-wave reduction, no sCtx, no extra barriers.
    f4 o = {0.f, 0.f, 0.f, 0.f};
    const int d = wave * 16 + l16;
    for (int ks = 0; ks < 64; ++ks) {
        const int t0 = ks * 32;
        short8 a = *(const short8*)(&sS[l16 * SSTR + t0 + quad * 8]);
        short8 bv;   // B[k=t][n=d]: lane = col d, elems = 8 consecutive t per quad
        if (BF16) {
            bv = *(const short8*)(vt + (size_t)d * S_LEN + t0 + quad * 8);
        } else {
            #pragma unroll
            for (int j = 0; j < 8; ++j)
                bv[j] = f2b(vp[(size_t)(t0 + quad * 8 + j) * D_K + d]);
        }
        o = __builtin_amdgcn_mfma_f32_16x16x32_bf16(a, bv, o, 0, 0, 0);
    }
    #pragma unroll
    for (int rr = 0; rr < 4; ++rr)
        cp[(size_t)(quad * 4 + rr) * D_K + d] = o[rr];
}

extern "C" void kernel_launch(void* const* d_in, const int* in_sizes, int n_in,
                              void* d_out, int out_size, void* d_ws, size_t ws_size,
                              hipStream_t stream) {
    const float* q = (const float*)d_in[0];
    const float* k = (const float*)d_in[1];
    const float* v = (const float*)d_in[2];
    const int* mask = (const int*)d_in[3];   // jnp.bool_ -> int32 per harness convention
    float* out = (float*)d_out;
    float* ctx  = out;                                     // (4,16,2048,64)
    float* attn = out + (size_t)4 * 16 * 2048 * 64;        // (4,16,2048,2048)

    const size_t KV_ELEMS = (size_t)4 * 16 * 2048 * 64;    // 8,388,608
    const size_t WS_NEED  = KV_ELEMS * 2 * sizeof(short);  // 33.6 MB

    if (d_ws && ws_size >= WS_NEED) {
        short* kb = (short*)d_ws;
        short* vt = kb + KV_ELEMS;
        transpose_cvt<<<dim3(2048), dim3(256), 0, stream>>>(k, kb, S_LEN, D_K, 0);
        transpose_cvt<<<dim3(2048), dim3(256), 0, stream>>>(v, vt, D_K, S_LEN, 1);
        attn_fused<true><<<dim3(8192), dim3(256), 0, stream>>>(q, k, v, kb, vt, mask, ctx, attn);
    } else {
        attn_fused<false><<<dim3(8192), dim3(256), 0, stream>>>(q, k, v, nullptr, nullptr, mask, ctx, attn);
    }
}